// Round 11
// baseline (57.723 us; speedup 1.0000x reference)
//
#include <hip/hip_runtime.h>
#include <hip/hip_bf16.h>
#include <math.h>

// SimCLR NT-Xent: B=4096, D=256, n=8192, T=0.5.
// z' = sqrt(K1) * rownorm(concat(a,b)) as bf16, row-swizzled:
//   stored_byte_in_row = logical_byte ^ ((row&7)<<4)
// MFMA(z', z'^T) = K1 * dot (K1 = 2*log2 e) -> exp(sim) = exp2(MFMA out).
// Round 11: rf=4 (64 rows/wave) + barrier-light pipeline.
//  - __launch_bounds__(512,1): hipcc's 2nd arg is min BLOCKS/CU (R10 lesson:
//    N=2 -> 4 waves/SIMD -> 128-VGPR cap -> spill). N=1 -> 256 cap.
//  - No intra-tile barriers: stages write buf (t+2)%3, reads hit buf t%3 —
//    no hazard. Dual bA/bB read sets; ds_reads for phase ct+1 + 1 stage
//    portion issue before the MFMA cluster on ct (compiler lgkmcnt overlaps).
//  - One vmcnt(4)+s_barrier per tile (certify t+1, keep t+2's 4 in flight).
// loss = mean( ln2 * (log2(S_i - exp2(self_i)) - K1*posdot_i) ).

#define NROWS 8192
#define BHALF 4096
#define DDIM  256
#define ROWB  512                 // bytes per bf16 row
#define JSPLIT 16
#define JCHUNK (NROWS / JSPLIT)   // 512 cols per block
#define JT 64                     // cols per tile
#define NTILES (JCHUNK / JT)      // 8
#define TILEB (JT * ROWB)         // 32 KiB per LDS buffer

#define SQRT_K1 1.6986436f        // sqrt(2*log2(e))
#define LN2F 0.6931471805599453f

typedef __attribute__((ext_vector_type(8))) __bf16 bf16x8;
typedef __attribute__((ext_vector_type(4))) float f32x4;

#if __has_builtin(__builtin_amdgcn_exp2f)
#define FEXP2(x) __builtin_amdgcn_exp2f(x)
#else
#define FEXP2(x) __exp2f(x)
#endif
#if __has_builtin(__builtin_amdgcn_logf)
#define FLOG2(x) __builtin_amdgcn_logf(x)
#else
#define FLOG2(x) __log2f(x)
#endif

__device__ __forceinline__ float bfu(unsigned short u) {
  union { unsigned v; float f; } x; x.v = ((unsigned)u) << 16; return x.f;
}

// ---------------- Kernel 1: normalize+scale rows -> swizzled bf16 ----------
__global__ __launch_bounds__(256) void norm_kernel(
    const float* __restrict__ a, const float* __restrict__ b,
    char* __restrict__ zb, float* __restrict__ selfdot) {
  int row = blockIdx.x * 4 + (threadIdx.x >> 6);
  int lane = threadIdx.x & 63;
  const float* src = (row < BHALF) ? (a + (size_t)row * DDIM)
                                   : (b + (size_t)(row - BHALF) * DDIM);
  float4 v = ((const float4*)src)[lane];
  float ss = v.x * v.x + v.y * v.y + v.z * v.z + v.w * v.w;
  #pragma unroll
  for (int m = 1; m < 64; m <<= 1) ss += __shfl_xor(ss, m, 64);
  float inv = rsqrtf(ss);
  inv = inv * (1.5f - 0.5f * ss * inv * inv);
  float sc = inv * SQRT_K1;   // bake sqrt(K1) into both operands

  union { __hip_bfloat16 h; unsigned short u; } c0, c1, c2, c3;
  c0.h = __float2bfloat16(v.x * sc);
  c1.h = __float2bfloat16(v.y * sc);
  c2.h = __float2bfloat16(v.z * sc);
  c3.h = __float2bfloat16(v.w * sc);
  // scaled self-dot of the bf16-rounded row (= what MFMA produces on diag)
  float q0 = bfu(c0.u), q1 = bfu(c1.u), q2 = bfu(c2.u), q3 = bfu(c3.u);
  float sq = q0 * q0 + q1 * q1 + q2 * q2 + q3 * q3;
  #pragma unroll
  for (int m = 1; m < 64; m <<= 1) sq += __shfl_xor(sq, m, 64);

  ushort4 o = make_ushort4(c0.u, c1.u, c2.u, c3.u);
  int off = row * ROWB + ((lane * 8) ^ ((row & 7) << 4));
  *(ushort4*)(zb + off) = o;
  if (lane == 0) selfdot[row] = sq;
}

// ---------------- Kernel 2: z z^T + exp2 row-sums, barrier-light -----------
// Grid (16 js, 16 rb), 512 thr = 8 waves x 64 rows. 1 block/CU.
__global__ __launch_bounds__(512, 1) void sim_kernel(
    const char* __restrict__ zb, float* __restrict__ s_part) {
  __shared__ __align__(16) char lds[3 * TILEB];  // 96 KiB, triple buffer
  int js = blockIdx.x;            // 0..15
  int rb = blockIdx.y;            // 0..15
  int wave = threadIdx.x >> 6;    // 0..7
  int lane = threadIdx.x & 63;
  int lrow = lane & 15;
  int kgrp = lane >> 4;
  int sw = (lrow & 7) << 4;
  int r0 = rb * 512 + wave * 64;
  int jbase = js * JCHUNK;

  int koff[8];
  #pragma unroll
  for (int kk = 0; kk < 8; ++kk) koff[kk] = (kk * 64 + kgrp * 16) ^ sw;

  // --- preload A fragments (64 rows x K=256), scaled z: 128 VGPRs ---
  bf16x8 af[4][8];
  #pragma unroll
  for (int rf = 0; rf < 4; ++rf) {
    const char* rp = zb + (size_t)(r0 + rf * 16 + lrow) * ROWB;
    #pragma unroll
    for (int kk = 0; kk < 8; ++kk)
      af[rf][kk] = *(const bf16x8*)(rp + koff[kk]);
  }

  float sacc[4][4] = {};
  f32x4 C0, C1, C2, C3;
  bf16x8 bA[8], bB[8];

  // stage one quarter (8KB) of a 64-col tile; LDS dest wave-uniform base
  #define STAGE1(dstbuf, j0, portion) do {                                    \
    const char* g_ = zb + (size_t)(j0) * ROWB + (portion) * 8192 +            \
                     wave * 1024 + lane * 16;                                 \
    char* l_ = lds + (dstbuf) * TILEB + (portion) * 8192 + wave * 1024;       \
    __builtin_amdgcn_global_load_lds(                                         \
        (const __attribute__((address_space(1))) void*)g_,                    \
        (__attribute__((address_space(3))) void*)l_, 16, 0, 0);               \
  } while (0)

  #define DSREAD(BV, ct) do {                                                 \
    const char* lbr = lds + buf * TILEB + (ct) * 8192 + lrow * ROWB;          \
    _Pragma("unroll")                                                         \
    for (int kk = 0; kk < 8; ++kk)                                            \
      BV[kk] = *(const bf16x8*)(lbr + koff[kk]);                              \
  } while (0)

  #define MFMA32(BV) do {                                                     \
    C0 = (f32x4){0.f, 0.f, 0.f, 0.f};                                         \
    C1 = (f32x4){0.f, 0.f, 0.f, 0.f};                                         \
    C2 = (f32x4){0.f, 0.f, 0.f, 0.f};                                         \
    C3 = (f32x4){0.f, 0.f, 0.f, 0.f};                                         \
    __builtin_amdgcn_s_setprio(1);                                            \
    _Pragma("unroll")                                                         \
    for (int kk = 0; kk < 8; ++kk) {                                          \
      C0 = __builtin_amdgcn_mfma_f32_16x16x32_bf16(af[0][kk], BV[kk], C0, 0, 0, 0); \
      C1 = __builtin_amdgcn_mfma_f32_16x16x32_bf16(af[1][kk], BV[kk], C1, 0, 0, 0); \
      C2 = __builtin_amdgcn_mfma_f32_16x16x32_bf16(af[2][kk], BV[kk], C2, 0, 0, 0); \
      C3 = __builtin_amdgcn_mfma_f32_16x16x32_bf16(af[3][kk], BV[kk], C3, 0, 0, 0); \
    }                                                                         \
    __builtin_amdgcn_s_setprio(0);                                            \
  } while (0)

  #define FLUSHC() do {                                                       \
    _Pragma("unroll")                                                         \
    for (int r = 0; r < 4; ++r) {                                             \
      sacc[0][r] += FEXP2(C0[r]);                                             \
      sacc[1][r] += FEXP2(C1[r]);                                             \
      sacc[2][r] += FEXP2(C2[r]);                                             \
      sacc[3][r] += FEXP2(C3[r]);                                             \
    }                                                                         \
  } while (0)

  // prologue: fully stage tiles 0 and 1; certify tile 0 (vmcnt(4))
  #pragma unroll
  for (int p = 0; p < 4; ++p) STAGE1(0, jbase, p);
  #pragma unroll
  for (int p = 0; p < 4; ++p) STAGE1(1, jbase + JT, p);
  asm volatile("s_waitcnt vmcnt(4)" ::: "memory");
  __builtin_amdgcn_sched_barrier(0);
  __builtin_amdgcn_s_barrier();

  int buf = 0;
  for (int t = 0; t < NTILES; ++t) {
    int dst = buf + 2; if (dst >= 3) dst -= 3;   // (t+2)%3
    bool st = (t + 2 < NTILES);
    // tile-start: read phase 0, issue stage portion 0
    DSREAD(bA, 0);
    if (st) STAGE1(dst, jbase + (t + 2) * JT, 0);
    // phase 0: prefetch ct1, stage p1, MFMA ct0, flush
    DSREAD(bB, 1);
    if (st) STAGE1(dst, jbase + (t + 2) * JT, 1);
    MFMA32(bA);
    FLUSHC();
    // phase 1
    DSREAD(bA, 2);
    if (st) STAGE1(dst, jbase + (t + 2) * JT, 2);
    MFMA32(bB);
    FLUSHC();
    // phase 2
    DSREAD(bB, 3);
    if (st) STAGE1(dst, jbase + (t + 2) * JT, 3);
    MFMA32(bA);
    FLUSHC();
    // phase 3
    MFMA32(bB);
    FLUSHC();
    // tile boundary: certify tile t+1 (own loads), then cross-wave barrier
    if (t + 1 < NTILES) {
      if (st)
        asm volatile("s_waitcnt vmcnt(4)" ::: "memory");
      else
        asm volatile("s_waitcnt vmcnt(0)" ::: "memory");
      __builtin_amdgcn_sched_barrier(0);
      __builtin_amdgcn_s_barrier();
    }
    ++buf; if (buf == 3) buf = 0;
  }
  #undef FLUSHC
  #undef MFMA32
  #undef DSREAD
  #undef STAGE1

  // reduce across the 16 column-lanes (C layout: col=lane&15, row=kgrp*4+r)
  #pragma unroll
  for (int rf = 0; rf < 4; ++rf) {
    #pragma unroll
    for (int r = 0; r < 4; ++r) {
      float v = sacc[rf][r];
      #pragma unroll
      for (int m = 1; m < 16; m <<= 1) v += __shfl_xor(v, m, 64);
      if (lrow == 0) {
        int grow = r0 + rf * 16 + kgrp * 4 + r;
        s_part[(size_t)grow * JSPLIT + js] = v;
      }
    }
  }
}

// ---------------- Kernel 3: per-row term (pos dot + assemble) --------------
// 512 blocks x 4 waves x 4 rows.
__global__ __launch_bounds__(256) void rowterm_kernel(
    const char* __restrict__ zb, const float* __restrict__ s_part,
    const float* __restrict__ selfdot, float* __restrict__ bpart) {
  int wave = threadIdx.x >> 6;
  int lane = threadIdx.x & 63;
  int rbase = blockIdx.x * 16 + wave * 4;
  float wacc = 0.f;
  #pragma unroll
  for (int rr = 0; rr < 4; ++rr) {
    int i = rbase + rr;
    int j = i ^ BHALF;                       // (i+B) mod 2B
    int wo = (lane * 8) ^ ((i & 7) << 4);    // j&7 == i&7 (4096 % 8 == 0)
    ushort4 zi = *(const ushort4*)(zb + (size_t)i * ROWB + wo);
    ushort4 zj = *(const ushort4*)(zb + (size_t)j * ROWB + wo);
    float dot = bfu(zi.x) * bfu(zj.x) + bfu(zi.y) * bfu(zj.y) +
                bfu(zi.z) * bfu(zj.z) + bfu(zi.w) * bfu(zj.w);
    float sp = (lane < JSPLIT) ? s_part[(size_t)i * JSPLIT + lane] : 0.f;
    #pragma unroll
    for (int m = 1; m < 64; m <<= 1) {
      dot += __shfl_xor(dot, m, 64);
      sp += __shfl_xor(sp, m, 64);
    }
    float S = sp - FEXP2(selfdot[i]);          // remove diagonal
    wacc += LN2F * (FLOG2(S) - dot);           // denom - pos (2's cancel)
  }
  __shared__ float red[4];
  if (lane == 0) red[wave] = wacc;
  __syncthreads();
  if (threadIdx.x == 0)
    bpart[blockIdx.x] = red[0] + red[1] + red[2] + red[3];
}

// ---------------- Kernel 4: final sum --------------------------------------
__global__ __launch_bounds__(512) void final_kernel(
    const float* __restrict__ bpart, float* __restrict__ out) {
  int t = threadIdx.x;  // 512 threads = 8 waves
  float v = bpart[t];
  #pragma unroll
  for (int m = 1; m < 64; m <<= 1) v += __shfl_xor(v, m, 64);
  __shared__ float r2[8];
  if ((t & 63) == 0) r2[t >> 6] = v;
  __syncthreads();
  if (t == 0) {
    float s = 0.f;
    #pragma unroll
    for (int w = 0; w < 8; ++w) s += r2[w];
    out[0] = s / (float)NROWS;
  }
}

// ---------------- Launcher --------------------------------------------------
extern "C" void kernel_launch(void* const* d_in, const int* in_sizes, int n_in,
                              void* d_out, int out_size, void* d_ws, size_t ws_size,
                              hipStream_t stream) {
  const float* a = (const float*)d_in[0];
  const float* b = (const float*)d_in[1];
  float* out = (float*)d_out;
  char* ws = (char*)d_ws;

  char* zb = ws;                                            // 4 MiB
  float* selfdot = (float*)(ws + (size_t)NROWS * ROWB);     // 32 KiB
  float* s_part = selfdot + NROWS;                          // 512 KiB
  float* bpart = s_part + (size_t)NROWS * JSPLIT;           // 2 KiB

  hipLaunchKernelGGL(norm_kernel, dim3(NROWS / 4), dim3(256), 0, stream,
                     a, b, zb, selfdot);
  hipLaunchKernelGGL(sim_kernel, dim3(JSPLIT, NROWS / 512), dim3(512), 0,
                     stream, zb, s_part);
  hipLaunchKernelGGL(rowterm_kernel, dim3(512), dim3(256), 0, stream,
                     zb, s_part, selfdot, bpart);
  hipLaunchKernelGGL(final_kernel, dim3(1), dim3(512), 0, stream, bpart, out);
}

// Round 12
// 48.097 us; speedup vs baseline: 1.2002x; 1.2002x over previous
//
#include <hip/hip_runtime.h>
#include <hip/hip_bf16.h>
#include <math.h>

// SimCLR NT-Xent: B=4096, D=256, n=8192, T=0.5.
// z' = sqrt(K1) * rownorm(concat(a,b)) as bf16, row-swizzled:
//   stored_byte_in_row = logical_byte ^ ((row&7)<<4)
// MFMA(z', z'^T) = K1 * dot (K1 = 2*log2 e) -> exp(sim) = exp2(MFMA out).
// Round 12: rf=4 in 256-THREAD blocks. R10/R11 lesson: 512-thr blocks are
// hard-capped at 128 VGPR (8 waves must co-reside -> 2/SIMD min) and the
// ~215-reg rf=4 body spills. 256-thr + __launch_bounds__(256,2) -> 256-VGPR
// cap, body fits (~215). LDS 2x32KB double buffer = 64KB/block -> 2
// blocks/CU (cross-block desync covers barrier/exp stalls; 4-wave barriers).
// Grid (32 rb, 16 js) = 512 = 2/CU, R3's proven L2 mapping. One
// vmcnt(0)+s_barrier per 64-col tile; stage portions interleaved 2/phase.
// loss = mean( ln2 * (log2(S_i - exp2(self_i)) - K1*posdot_i) ).

#define NROWS 8192
#define BHALF 4096
#define DDIM  256
#define ROWB  512                 // bytes per bf16 row
#define JSPLIT 16
#define JCHUNK (NROWS / JSPLIT)   // 512 cols per block
#define JT 64                     // cols per tile
#define NTILES (JCHUNK / JT)      // 8
#define TILEB (JT * ROWB)         // 32 KiB per LDS buffer

#define SQRT_K1 1.6986436f        // sqrt(2*log2(e))
#define LN2F 0.6931471805599453f

typedef __attribute__((ext_vector_type(8))) __bf16 bf16x8;
typedef __attribute__((ext_vector_type(4))) float f32x4;

#if __has_builtin(__builtin_amdgcn_exp2f)
#define FEXP2(x) __builtin_amdgcn_exp2f(x)
#else
#define FEXP2(x) __exp2f(x)
#endif
#if __has_builtin(__builtin_amdgcn_logf)
#define FLOG2(x) __builtin_amdgcn_logf(x)
#else
#define FLOG2(x) __log2f(x)
#endif

__device__ __forceinline__ float bfu(unsigned short u) {
  union { unsigned v; float f; } x; x.v = ((unsigned)u) << 16; return x.f;
}

// ---------------- Kernel 1: normalize+scale rows -> swizzled bf16 ----------
__global__ __launch_bounds__(256) void norm_kernel(
    const float* __restrict__ a, const float* __restrict__ b,
    char* __restrict__ zb, float* __restrict__ selfdot) {
  int row = blockIdx.x * 4 + (threadIdx.x >> 6);
  int lane = threadIdx.x & 63;
  const float* src = (row < BHALF) ? (a + (size_t)row * DDIM)
                                   : (b + (size_t)(row - BHALF) * DDIM);
  float4 v = ((const float4*)src)[lane];
  float ss = v.x * v.x + v.y * v.y + v.z * v.z + v.w * v.w;
  #pragma unroll
  for (int m = 1; m < 64; m <<= 1) ss += __shfl_xor(ss, m, 64);
  float inv = rsqrtf(ss);
  inv = inv * (1.5f - 0.5f * ss * inv * inv);
  float sc = inv * SQRT_K1;   // bake sqrt(K1) into both operands

  union { __hip_bfloat16 h; unsigned short u; } c0, c1, c2, c3;
  c0.h = __float2bfloat16(v.x * sc);
  c1.h = __float2bfloat16(v.y * sc);
  c2.h = __float2bfloat16(v.z * sc);
  c3.h = __float2bfloat16(v.w * sc);
  // scaled self-dot of the bf16-rounded row (= what MFMA produces on diag)
  float q0 = bfu(c0.u), q1 = bfu(c1.u), q2 = bfu(c2.u), q3 = bfu(c3.u);
  float sq = q0 * q0 + q1 * q1 + q2 * q2 + q3 * q3;
  #pragma unroll
  for (int m = 1; m < 64; m <<= 1) sq += __shfl_xor(sq, m, 64);

  ushort4 o = make_ushort4(c0.u, c1.u, c2.u, c3.u);
  int off = row * ROWB + ((lane * 8) ^ ((row & 7) << 4));
  *(ushort4*)(zb + off) = o;
  if (lane == 0) selfdot[row] = sq;
}

// ---------------- Kernel 2: z z^T + exp2 row-sums ---------------------------
// Grid (32 rb, 16 js), 256 thr = 4 waves x 64 rows (rf=4). 2 blocks/CU.
__global__ __launch_bounds__(256, 2) void sim_kernel(
    const char* __restrict__ zb, float* __restrict__ s_part) {
  __shared__ __align__(16) char lds[2 * TILEB];  // 64 KiB double buffer
  int rb = blockIdx.x;            // 0..31
  int js = blockIdx.y;            // 0..15
  int wave = threadIdx.x >> 6;    // 0..3
  int lane = threadIdx.x & 63;
  int lrow = lane & 15;
  int kgrp = lane >> 4;
  int sw = (lrow & 7) << 4;
  int r0 = rb * 256 + wave * 64;
  int jbase = js * JCHUNK;

  int koff[8];
  #pragma unroll
  for (int kk = 0; kk < 8; ++kk) koff[kk] = (kk * 64 + kgrp * 16) ^ sw;

  // --- preload A fragments (64 rows x K=256), scaled z: 128 VGPRs ---
  bf16x8 af[4][8];
  #pragma unroll
  for (int rf = 0; rf < 4; ++rf) {
    const char* rp = zb + (size_t)(r0 + rf * 16 + lrow) * ROWB;
    #pragma unroll
    for (int kk = 0; kk < 8; ++kk)
      af[rf][kk] = *(const bf16x8*)(rp + koff[kk]);
  }

  float sacc[4][4] = {};
  f32x4 C0, C1, C2, C3;
  bf16x8 bfv[8];

  // stage one eighth (4KB) of a 64-col tile; LDS dest wave-uniform base
  #define STAGE1(dstbuf, j0, portion) do {                                    \
    const char* g_ = zb + (size_t)(j0) * ROWB + (portion) * 4096 +            \
                     wave * 1024 + lane * 16;                                 \
    char* l_ = lds + (dstbuf) * TILEB + (portion) * 4096 + wave * 1024;       \
    __builtin_amdgcn_global_load_lds(                                         \
        (const __attribute__((address_space(1))) void*)g_,                    \
        (__attribute__((address_space(3))) void*)l_, 16, 0, 0);               \
  } while (0)

  #define DSREAD(ct) do {                                                     \
    const char* lbr = lds + buf * TILEB + (ct) * 8192 + lrow * ROWB;          \
    _Pragma("unroll")                                                         \
    for (int kk = 0; kk < 8; ++kk)                                            \
      bfv[kk] = *(const bf16x8*)(lbr + koff[kk]);                             \
  } while (0)

  #define MFMA32() do {                                                       \
    C0 = (f32x4){0.f, 0.f, 0.f, 0.f};                                         \
    C1 = (f32x4){0.f, 0.f, 0.f, 0.f};                                         \
    C2 = (f32x4){0.f, 0.f, 0.f, 0.f};                                         \
    C3 = (f32x4){0.f, 0.f, 0.f, 0.f};                                         \
    __builtin_amdgcn_s_setprio(1);                                            \
    _Pragma("unroll")                                                         \
    for (int kk = 0; kk < 8; ++kk) {                                          \
      C0 = __builtin_amdgcn_mfma_f32_16x16x32_bf16(af[0][kk], bfv[kk], C0, 0, 0, 0); \
      C1 = __builtin_amdgcn_mfma_f32_16x16x32_bf16(af[1][kk], bfv[kk], C1, 0, 0, 0); \
      C2 = __builtin_amdgcn_mfma_f32_16x16x32_bf16(af[2][kk], bfv[kk], C2, 0, 0, 0); \
      C3 = __builtin_amdgcn_mfma_f32_16x16x32_bf16(af[3][kk], bfv[kk], C3, 0, 0, 0); \
    }                                                                         \
    __builtin_amdgcn_s_setprio(0);                                            \
  } while (0)

  #define FLUSHC() do {                                                       \
    _Pragma("unroll")                                                         \
    for (int r = 0; r < 4; ++r) {                                             \
      sacc[0][r] += FEXP2(C0[r]);                                             \
      sacc[1][r] += FEXP2(C1[r]);                                             \
      sacc[2][r] += FEXP2(C2[r]);                                             \
      sacc[3][r] += FEXP2(C3[r]);                                             \
    }                                                                         \
  } while (0)

  // prologue: stage tile 0 fully (8 portions), drain, barrier
  #pragma unroll
  for (int p = 0; p < 8; ++p) STAGE1(0, jbase, p);
  asm volatile("s_waitcnt vmcnt(0)" ::: "memory");
  __builtin_amdgcn_sched_barrier(0);
  __builtin_amdgcn_s_barrier();

  int buf = 0;
  for (int t = 0; t < NTILES; ++t) {
    bool st = (t + 1 < NTILES);
    int nj = jbase + (t + 1) * JT;
    // 4 phases of 16 cols; stage 2 portions of tile t+1 per phase
    #pragma unroll
    for (int ct = 0; ct < 4; ++ct) {
      DSREAD(ct);
      if (st) {
        STAGE1(buf ^ 1, nj, 2 * ct);
        STAGE1(buf ^ 1, nj, 2 * ct + 1);
      }
      MFMA32();
      FLUSHC();
    }
    // tile boundary: certify tile t+1's LDS, sync readers/writers of buf
    if (st) {
      asm volatile("s_waitcnt vmcnt(0)" ::: "memory");
      __builtin_amdgcn_sched_barrier(0);
      __builtin_amdgcn_s_barrier();
    }
    buf ^= 1;
  }
  #undef FLUSHC
  #undef MFMA32
  #undef DSREAD
  #undef STAGE1

  // reduce across the 16 column-lanes (C layout: col=lane&15, row=kgrp*4+r)
  #pragma unroll
  for (int rf = 0; rf < 4; ++rf) {
    #pragma unroll
    for (int r = 0; r < 4; ++r) {
      float v = sacc[rf][r];
      #pragma unroll
      for (int m = 1; m < 16; m <<= 1) v += __shfl_xor(v, m, 64);
      if (lrow == 0) {
        int grow = r0 + rf * 16 + kgrp * 4 + r;
        s_part[(size_t)grow * JSPLIT + js] = v;
      }
    }
  }
}

// ---------------- Kernel 3: per-row term (pos dot + assemble) --------------
// 512 blocks x 4 waves x 4 rows.
__global__ __launch_bounds__(256) void rowterm_kernel(
    const char* __restrict__ zb, const float* __restrict__ s_part,
    const float* __restrict__ selfdot, float* __restrict__ bpart) {
  int wave = threadIdx.x >> 6;
  int lane = threadIdx.x & 63;
  int rbase = blockIdx.x * 16 + wave * 4;
  float wacc = 0.f;
  #pragma unroll
  for (int rr = 0; rr < 4; ++rr) {
    int i = rbase + rr;
    int j = i ^ BHALF;                       // (i+B) mod 2B
    int wo = (lane * 8) ^ ((i & 7) << 4);    // j&7 == i&7 (4096 % 8 == 0)
    ushort4 zi = *(const ushort4*)(zb + (size_t)i * ROWB + wo);
    ushort4 zj = *(const ushort4*)(zb + (size_t)j * ROWB + wo);
    float dot = bfu(zi.x) * bfu(zj.x) + bfu(zi.y) * bfu(zj.y) +
                bfu(zi.z) * bfu(zj.z) + bfu(zi.w) * bfu(zj.w);
    float sp = (lane < JSPLIT) ? s_part[(size_t)i * JSPLIT + lane] : 0.f;
    #pragma unroll
    for (int m = 1; m < 64; m <<= 1) {
      dot += __shfl_xor(dot, m, 64);
      sp += __shfl_xor(sp, m, 64);
    }
    float S = sp - FEXP2(selfdot[i]);          // remove diagonal
    wacc += LN2F * (FLOG2(S) - dot);           // denom - pos (2's cancel)
  }
  __shared__ float red[4];
  if (lane == 0) red[wave] = wacc;
  __syncthreads();
  if (threadIdx.x == 0)
    bpart[blockIdx.x] = red[0] + red[1] + red[2] + red[3];
}

// ---------------- Kernel 4: final sum --------------------------------------
__global__ __launch_bounds__(512) void final_kernel(
    const float* __restrict__ bpart, float* __restrict__ out) {
  int t = threadIdx.x;  // 512 threads = 8 waves
  float v = bpart[t];
  #pragma unroll
  for (int m = 1; m < 64; m <<= 1) v += __shfl_xor(v, m, 64);
  __shared__ float r2[8];
  if ((t & 63) == 0) r2[t >> 6] = v;
  __syncthreads();
  if (t == 0) {
    float s = 0.f;
    #pragma unroll
    for (int w = 0; w < 8; ++w) s += r2[w];
    out[0] = s / (float)NROWS;
  }
}

// ---------------- Launcher --------------------------------------------------
extern "C" void kernel_launch(void* const* d_in, const int* in_sizes, int n_in,
                              void* d_out, int out_size, void* d_ws, size_t ws_size,
                              hipStream_t stream) {
  const float* a = (const float*)d_in[0];
  const float* b = (const float*)d_in[1];
  float* out = (float*)d_out;
  char* ws = (char*)d_ws;

  char* zb = ws;                                            // 4 MiB
  float* selfdot = (float*)(ws + (size_t)NROWS * ROWB);     // 32 KiB
  float* s_part = selfdot + NROWS;                          // 512 KiB
  float* bpart = s_part + (size_t)NROWS * JSPLIT;           // 2 KiB

  hipLaunchKernelGGL(norm_kernel, dim3(NROWS / 4), dim3(256), 0, stream,
                     a, b, zb, selfdot);
  hipLaunchKernelGGL(sim_kernel, dim3(NROWS / 256, JSPLIT), dim3(256), 0,
                     stream, zb, s_part);
  hipLaunchKernelGGL(rowterm_kernel, dim3(512), dim3(256), 0, stream,
                     zb, s_part, selfdot, bpart);
  hipLaunchKernelGGL(final_kernel, dim3(1), dim3(512), 0, stream, bpart, out);
}

// Round 13
// 47.785 us; speedup vs baseline: 1.2080x; 1.0065x over previous
//
#include <hip/hip_runtime.h>
#include <hip/hip_bf16.h>
#include <math.h>

// SimCLR NT-Xent: B=4096, D=256, n=8192, T=0.5.
// z' = sqrt(K1) * rownorm(concat(a,b)) as bf16, row-swizzled in global:
//   stored_byte_in_row = logical_byte ^ ((row&7)<<4)
// MFMA(z', z'^T) = K1 * dot (K1 = 2*log2 e) -> exp(sim) = exp2(MFMA out).
// Round 13 = R12 + FRAGMENT-ORDER LDS for B:
//   Every wave consumes identical B fragments (frag index = lane only), so
//   LDS holds B pre-arranged as slot[(ct*8+kk)*1024 + lane*16]. ds_read_b128
//   is then lane-sequential across banks -> ZERO conflicts (R12 measured 4
//   extra cyc/read: 2.1M conflict cycles, making LDS pipe co-critical with
//   MFMA). global_load_lds does the gather: per-lane SOURCE address carries
//   the col/kgrp/swizzle permutation; LDS dest stays linear base+lane*16.
// loss = mean( ln2 * (log2(S_i - exp2(self_i)) - K1*posdot_i) ).

#define NROWS 8192
#define BHALF 4096
#define DDIM  256
#define ROWB  512                 // bytes per bf16 row
#define JSPLIT 16
#define JCHUNK (NROWS / JSPLIT)   // 512 cols per block
#define JT 64                     // cols per tile
#define NTILES (JCHUNK / JT)      // 8
#define TILEB (JT * ROWB)         // 32 KiB per LDS buffer

#define SQRT_K1 1.6986436f        // sqrt(2*log2(e))
#define LN2F 0.6931471805599453f

typedef __attribute__((ext_vector_type(8))) __bf16 bf16x8;
typedef __attribute__((ext_vector_type(4))) float f32x4;

#if __has_builtin(__builtin_amdgcn_exp2f)
#define FEXP2(x) __builtin_amdgcn_exp2f(x)
#else
#define FEXP2(x) __exp2f(x)
#endif
#if __has_builtin(__builtin_amdgcn_logf)
#define FLOG2(x) __builtin_amdgcn_logf(x)
#else
#define FLOG2(x) __log2f(x)
#endif

__device__ __forceinline__ float bfu(unsigned short u) {
  union { unsigned v; float f; } x; x.v = ((unsigned)u) << 16; return x.f;
}

// ---------------- Kernel 1: normalize+scale rows -> swizzled bf16 ----------
__global__ __launch_bounds__(256) void norm_kernel(
    const float* __restrict__ a, const float* __restrict__ b,
    char* __restrict__ zb, float* __restrict__ selfdot) {
  int row = blockIdx.x * 4 + (threadIdx.x >> 6);
  int lane = threadIdx.x & 63;
  const float* src = (row < BHALF) ? (a + (size_t)row * DDIM)
                                   : (b + (size_t)(row - BHALF) * DDIM);
  float4 v = ((const float4*)src)[lane];
  float ss = v.x * v.x + v.y * v.y + v.z * v.z + v.w * v.w;
  #pragma unroll
  for (int m = 1; m < 64; m <<= 1) ss += __shfl_xor(ss, m, 64);
  float inv = rsqrtf(ss);
  inv = inv * (1.5f - 0.5f * ss * inv * inv);
  float sc = inv * SQRT_K1;   // bake sqrt(K1) into both operands

  union { __hip_bfloat16 h; unsigned short u; } c0, c1, c2, c3;
  c0.h = __float2bfloat16(v.x * sc);
  c1.h = __float2bfloat16(v.y * sc);
  c2.h = __float2bfloat16(v.z * sc);
  c3.h = __float2bfloat16(v.w * sc);
  // scaled self-dot of the bf16-rounded row (= what MFMA produces on diag)
  float q0 = bfu(c0.u), q1 = bfu(c1.u), q2 = bfu(c2.u), q3 = bfu(c3.u);
  float sq = q0 * q0 + q1 * q1 + q2 * q2 + q3 * q3;
  #pragma unroll
  for (int m = 1; m < 64; m <<= 1) sq += __shfl_xor(sq, m, 64);

  ushort4 o = make_ushort4(c0.u, c1.u, c2.u, c3.u);
  int off = row * ROWB + ((lane * 8) ^ ((row & 7) << 4));
  *(ushort4*)(zb + off) = o;
  if (lane == 0) selfdot[row] = sq;
}

// ---------------- Kernel 2: z z^T + exp2 row-sums ---------------------------
// Grid (32 rb, 16 js), 256 thr = 4 waves x 64 rows (rf=4). 2 blocks/CU.
// B staged in LDS in FRAGMENT ORDER: slot (ct*8+kk)*1024 + lane*16.
__global__ __launch_bounds__(256, 2) void sim_kernel(
    const char* __restrict__ zb, float* __restrict__ s_part) {
  __shared__ __align__(16) char lds[2 * TILEB];  // 64 KiB double buffer
  int rb = blockIdx.x;            // 0..31
  int js = blockIdx.y;            // 0..15
  int wave = threadIdx.x >> 6;    // 0..3
  int lane = threadIdx.x & 63;
  int lrow = lane & 15;
  int kgrp = lane >> 4;
  int r0 = rb * 256 + wave * 64;
  int jbase = js * JCHUNK;

  // --- preload A fragments (64 rows x K=256), swizzled global reads ---
  bf16x8 af[4][8];
  {
    int sw = (lrow & 7) << 4;
    #pragma unroll
    for (int rf = 0; rf < 4; ++rf) {
      const char* rp = zb + (size_t)(r0 + rf * 16 + lrow) * ROWB;
      #pragma unroll
      for (int kk = 0; kk < 8; ++kk)
        af[rf][kk] = *(const bf16x8*)(rp + ((kk * 64 + kgrp * 16) ^ sw));
    }
  }

  float sacc[4][4] = {};
  f32x4 C0, C1, C2, C3;
  bf16x8 bfv[8];

  // stage ONE fragment slot (1 KiB = 1 wave x 16B) of tile j0 into LDS
  // fragment-order slot (myct*8 + kk). Source: col = j0 + myct*16 + lrow,
  // bytes (kk*64 + kgrp*16) ^ row-swizzle. LDS dest linear: base + lane*16.
  #define STAGE_SLOT(dstbuf, j0, kkh) do {                                    \
    const char* g_ = zb +                                                     \
        (size_t)((j0) + wave * 16 + lrow) * ROWB +                            \
        (((kkh) * 64 + kgrp * 16) ^ ((lane & 7) << 4));                       \
    char* l_ = lds + (dstbuf) * TILEB + (wave * 8 + (kkh)) * 1024;            \
    __builtin_amdgcn_global_load_lds(                                         \
        (const __attribute__((address_space(1))) void*)g_,                    \
        (__attribute__((address_space(3))) void*)l_, 16, 0, 0);               \
  } while (0)

  // conflict-free fragment reads: lane-sequential 16B, compile-time offsets
  #define DSREAD(ct) do {                                                     \
    const char* lbr = lds + buf * TILEB + lane * 16;                          \
    _Pragma("unroll")                                                         \
    for (int kk = 0; kk < 8; ++kk)                                            \
      bfv[kk] = *(const bf16x8*)(lbr + ((ct) * 8 + kk) * 1024);               \
  } while (0)

  #define MFMA32() do {                                                       \
    C0 = (f32x4){0.f, 0.f, 0.f, 0.f};                                         \
    C1 = (f32x4){0.f, 0.f, 0.f, 0.f};                                         \
    C2 = (f32x4){0.f, 0.f, 0.f, 0.f};                                         \
    C3 = (f32x4){0.f, 0.f, 0.f, 0.f};                                         \
    __builtin_amdgcn_s_setprio(1);                                            \
    _Pragma("unroll")                                                         \
    for (int kk = 0; kk < 8; ++kk) {                                          \
      C0 = __builtin_amdgcn_mfma_f32_16x16x32_bf16(af[0][kk], bfv[kk], C0, 0, 0, 0); \
      C1 = __builtin_amdgcn_mfma_f32_16x16x32_bf16(af[1][kk], bfv[kk], C1, 0, 0, 0); \
      C2 = __builtin_amdgcn_mfma_f32_16x16x32_bf16(af[2][kk], bfv[kk], C2, 0, 0, 0); \
      C3 = __builtin_amdgcn_mfma_f32_16x16x32_bf16(af[3][kk], bfv[kk], C3, 0, 0, 0); \
    }                                                                         \
    __builtin_amdgcn_s_setprio(0);                                            \
  } while (0)

  #define FLUSHC() do {                                                       \
    _Pragma("unroll")                                                         \
    for (int r = 0; r < 4; ++r) {                                             \
      sacc[0][r] += FEXP2(C0[r]);                                             \
      sacc[1][r] += FEXP2(C1[r]);                                             \
      sacc[2][r] += FEXP2(C2[r]);                                             \
      sacc[3][r] += FEXP2(C3[r]);                                             \
    }                                                                         \
  } while (0)

  // prologue: stage tile 0 fully (each wave: its 8 slots), drain, barrier
  #pragma unroll
  for (int kk = 0; kk < 8; ++kk) STAGE_SLOT(0, jbase, kk);
  asm volatile("s_waitcnt vmcnt(0)" ::: "memory");
  __builtin_amdgcn_sched_barrier(0);
  __builtin_amdgcn_s_barrier();

  int buf = 0;
  for (int t = 0; t < NTILES; ++t) {
    bool st = (t + 1 < NTILES);
    int nj = jbase + (t + 1) * JT;
    // 4 phases of 16 cols; each phase stages 2 slots of tile t+1
    #pragma unroll
    for (int ct = 0; ct < 4; ++ct) {
      DSREAD(ct);
      if (st) {
        STAGE_SLOT(buf ^ 1, nj, 2 * ct);
        STAGE_SLOT(buf ^ 1, nj, 2 * ct + 1);
      }
      MFMA32();
      FLUSHC();
    }
    // tile boundary: loads for t+1 were issued 1-4 phases ago -> cheap drain
    if (st) {
      asm volatile("s_waitcnt vmcnt(0)" ::: "memory");
      __builtin_amdgcn_sched_barrier(0);
      __builtin_amdgcn_s_barrier();
    }
    buf ^= 1;
  }
  #undef FLUSHC
  #undef MFMA32
  #undef DSREAD
  #undef STAGE_SLOT

  // reduce across the 16 column-lanes (C layout: col=lane&15, row=kgrp*4+r)
  #pragma unroll
  for (int rf = 0; rf < 4; ++rf) {
    #pragma unroll
    for (int r = 0; r < 4; ++r) {
      float v = sacc[rf][r];
      #pragma unroll
      for (int m = 1; m < 16; m <<= 1) v += __shfl_xor(v, m, 64);
      if (lrow == 0) {
        int grow = r0 + rf * 16 + kgrp * 4 + r;
        s_part[(size_t)grow * JSPLIT + js] = v;
      }
    }
  }
}

// ---------------- Kernel 3: per-row term (pos dot + assemble) --------------
// 512 blocks x 4 waves x 4 rows.
__global__ __launch_bounds__(256) void rowterm_kernel(
    const char* __restrict__ zb, const float* __restrict__ s_part,
    const float* __restrict__ selfdot, float* __restrict__ bpart) {
  int wave = threadIdx.x >> 6;
  int lane = threadIdx.x & 63;
  int rbase = blockIdx.x * 16 + wave * 4;
  float wacc = 0.f;
  #pragma unroll
  for (int rr = 0; rr < 4; ++rr) {
    int i = rbase + rr;
    int j = i ^ BHALF;                       // (i+B) mod 2B
    int wo = (lane * 8) ^ ((i & 7) << 4);    // j&7 == i&7 (4096 % 8 == 0)
    ushort4 zi = *(const ushort4*)(zb + (size_t)i * ROWB + wo);
    ushort4 zj = *(const ushort4*)(zb + (size_t)j * ROWB + wo);
    float dot = bfu(zi.x) * bfu(zj.x) + bfu(zi.y) * bfu(zj.y) +
                bfu(zi.z) * bfu(zj.z) + bfu(zi.w) * bfu(zj.w);
    float sp = (lane < JSPLIT) ? s_part[(size_t)i * JSPLIT + lane] : 0.f;
    #pragma unroll
    for (int m = 1; m < 64; m <<= 1) {
      dot += __shfl_xor(dot, m, 64);
      sp += __shfl_xor(sp, m, 64);
    }
    float S = sp - FEXP2(selfdot[i]);          // remove diagonal
    wacc += LN2F * (FLOG2(S) - dot);           // denom - pos (2's cancel)
  }
  __shared__ float red[4];
  if (lane == 0) red[wave] = wacc;
  __syncthreads();
  if (threadIdx.x == 0)
    bpart[blockIdx.x] = red[0] + red[1] + red[2] + red[3];
}

// ---------------- Kernel 4: final sum --------------------------------------
__global__ __launch_bounds__(512) void final_kernel(
    const float* __restrict__ bpart, float* __restrict__ out) {
  int t = threadIdx.x;  // 512 threads = 8 waves
  float v = bpart[t];
  #pragma unroll
  for (int m = 1; m < 64; m <<= 1) v += __shfl_xor(v, m, 64);
  __shared__ float r2[8];
  if ((t & 63) == 0) r2[t >> 6] = v;
  __syncthreads();
  if (t == 0) {
    float s = 0.f;
    #pragma unroll
    for (int w = 0; w < 8; ++w) s += r2[w];
    out[0] = s / (float)NROWS;
  }
}

// ---------------- Launcher --------------------------------------------------
extern "C" void kernel_launch(void* const* d_in, const int* in_sizes, int n_in,
                              void* d_out, int out_size, void* d_ws, size_t ws_size,
                              hipStream_t stream) {
  const float* a = (const float*)d_in[0];
  const float* b = (const float*)d_in[1];
  float* out = (float*)d_out;
  char* ws = (char*)d_ws;

  char* zb = ws;                                            // 4 MiB
  float* selfdot = (float*)(ws + (size_t)NROWS * ROWB);     // 32 KiB
  float* s_part = selfdot + NROWS;                          // 512 KiB
  float* bpart = s_part + (size_t)NROWS * JSPLIT;           // 2 KiB

  hipLaunchKernelGGL(norm_kernel, dim3(NROWS / 4), dim3(256), 0, stream,
                     a, b, zb, selfdot);
  hipLaunchKernelGGL(sim_kernel, dim3(NROWS / 256, JSPLIT), dim3(256), 0,
                     stream, zb, s_part);
  hipLaunchKernelGGL(rowterm_kernel, dim3(512), dim3(256), 0, stream,
                     zb, s_part, selfdot, bpart);
  hipLaunchKernelGGL(final_kernel, dim3(1), dim3(512), 0, stream, bpart, out);
}

// Round 14
// 43.588 us; speedup vs baseline: 1.3243x; 1.0963x over previous
//
#include <hip/hip_runtime.h>
#include <hip/hip_bf16.h>
#include <math.h>

// SimCLR NT-Xent: B=4096, D=256, n=8192, T=0.5.
// z' = sqrt(K1) * rownorm(concat(a,b)) as bf16, row-swizzled in global:
//   stored_byte_in_row = logical_byte ^ ((row&7)<<4)
// MFMA(z', z'^T) = K1 * dot -> exp(sim) = exp2(MFMA out).  E is SYMMETRIC.
// Round 14 = R13 pipeline + TRIANGULAR circulant cover (half the MFMA):
//   square = 256x256. Block (t,gg): square (rows t*256, cols u=(t+gg)%32*256).
//   gg=0: diagonal square (row-sums only). gg=1..15: row-sums (slot gg) AND
//   col-sums (slot 19+gg) harvested -> each unordered pair computed once.
//   Antipodal (distance 16) squares computed from BOTH sides, row-sums only:
//   gg<4 blocks carry one extra 64-col JT-tile of square (t, t+16), partial
//   row-sums -> slot 16+gg. Every row gets slots 0..34 exactly once.
//   Load balance: heavy (5-JT) blocks at bid 0..127 pair with light blocks
//   on a CU (9 JT vs 8.5 avg). 2 blocks/CU.
// loss = mean( ln2 * (log2(S_i - exp2(self_i)) - K1*posdot_i) ).

#define NROWS 8192
#define BHALF 4096
#define DDIM  256
#define ROWB  512                 // bytes per bf16 row
#define JT    64                  // cols per JT-tile
#define TILEB (JT * ROWB)         // 32 KiB per LDS buffer
#define NSLOT 35
#define SSTRIDE 40                // s_part row stride (floats)

#define SQRT_K1 1.6986436f        // sqrt(2*log2(e))
#define LN2F 0.6931471805599453f

typedef __attribute__((ext_vector_type(8))) __bf16 bf16x8;
typedef __attribute__((ext_vector_type(4))) float f32x4;

#if __has_builtin(__builtin_amdgcn_exp2f)
#define FEXP2(x) __builtin_amdgcn_exp2f(x)
#else
#define FEXP2(x) __exp2f(x)
#endif
#if __has_builtin(__builtin_amdgcn_logf)
#define FLOG2(x) __builtin_amdgcn_logf(x)
#else
#define FLOG2(x) __log2f(x)
#endif

__device__ __forceinline__ float bfu(unsigned short u) {
  union { unsigned v; float f; } x; x.v = ((unsigned)u) << 16; return x.f;
}

// ---------------- Kernel 1: normalize+scale rows -> swizzled bf16 ----------
__global__ __launch_bounds__(256) void norm_kernel(
    const float* __restrict__ a, const float* __restrict__ b,
    char* __restrict__ zb, float* __restrict__ selfdot) {
  int row = blockIdx.x * 4 + (threadIdx.x >> 6);
  int lane = threadIdx.x & 63;
  const float* src = (row < BHALF) ? (a + (size_t)row * DDIM)
                                   : (b + (size_t)(row - BHALF) * DDIM);
  float4 v = ((const float4*)src)[lane];
  float ss = v.x * v.x + v.y * v.y + v.z * v.z + v.w * v.w;
  #pragma unroll
  for (int m = 1; m < 64; m <<= 1) ss += __shfl_xor(ss, m, 64);
  float inv = rsqrtf(ss);
  inv = inv * (1.5f - 0.5f * ss * inv * inv);
  float sc = inv * SQRT_K1;

  union { __hip_bfloat16 h; unsigned short u; } c0, c1, c2, c3;
  c0.h = __float2bfloat16(v.x * sc);
  c1.h = __float2bfloat16(v.y * sc);
  c2.h = __float2bfloat16(v.z * sc);
  c3.h = __float2bfloat16(v.w * sc);
  float q0 = bfu(c0.u), q1 = bfu(c1.u), q2 = bfu(c2.u), q3 = bfu(c3.u);
  float sq = q0 * q0 + q1 * q1 + q2 * q2 + q3 * q3;
  #pragma unroll
  for (int m = 1; m < 64; m <<= 1) sq += __shfl_xor(sq, m, 64);

  ushort4 o = make_ushort4(c0.u, c1.u, c2.u, c3.u);
  int off = row * ROWB + ((lane * 8) ^ ((row & 7) << 4));
  *(ushort4*)(zb + off) = o;
  if (lane == 0) selfdot[row] = sq;
}

// ---------------- Kernel 2: triangular z z^T + exp2 sums --------------------
// 512 blocks x 256 thr (4 waves x 64 rows, rf=4). bid<128 = heavy (5 JT).
__global__ __launch_bounds__(256, 2) void sim_kernel(
    const char* __restrict__ zb, float* __restrict__ s_part) {
  __shared__ __align__(16) char lds[2 * TILEB];   // 64 KiB double buffer
  __shared__ float cred[2][4][64];                // 2 KiB, parity-banked

  int bid = blockIdx.x;
  bool heavy = (bid < 128);
  int t  = heavy ? (bid & 31) : ((bid - 128) & 31);
  int gg = heavy ? (bid >> 5) : (4 + ((bid - 128) >> 5));
  int NJT = heavy ? 5 : 4;
  int ustrip = (t + gg) & 31;          // strip square col-tile
  int u16 = (t + 16) & 31;             // antipodal col-tile

  int wave = threadIdx.x >> 6;
  int lane = threadIdx.x & 63;
  int lrow = lane & 15;
  int kgrp = lane >> 4;
  int r0 = t * 256 + wave * 64;

  // --- preload A fragments (64 rows x K=256), swizzled global reads ---
  bf16x8 af[4][8];
  {
    int sw = (lrow & 7) << 4;
    #pragma unroll
    for (int rf = 0; rf < 4; ++rf) {
      const char* rp = zb + (size_t)(r0 + rf * 16 + lrow) * ROWB;
      #pragma unroll
      for (int kk = 0; kk < 8; ++kk)
        af[rf][kk] = *(const bf16x8*)(rp + ((kk * 64 + kgrp * 16) ^ sw));
    }
  }

  float sacc[4][4] = {};
  float cacc[4] = {};
  f32x4 C0, C1, C2, C3;
  bf16x8 bfv[8];

  #define STAGE_SLOT(dstbuf, j0, kkh) do {                                    \
    const char* g_ = zb +                                                     \
        (size_t)((j0) + wave * 16 + lrow) * ROWB +                            \
        (((kkh) * 64 + kgrp * 16) ^ ((lane & 7) << 4));                       \
    char* l_ = lds + (dstbuf) * TILEB + (wave * 8 + (kkh)) * 1024;            \
    __builtin_amdgcn_global_load_lds(                                         \
        (const __attribute__((address_space(1))) void*)g_,                    \
        (__attribute__((address_space(3))) void*)l_, 16, 0, 0);               \
  } while (0)

  #define DSREAD(bufi, ct) do {                                               \
    const char* lbr = lds + (bufi) * TILEB + lane * 16;                       \
    _Pragma("unroll")                                                         \
    for (int kk = 0; kk < 8; ++kk)                                            \
      bfv[kk] = *(const bf16x8*)(lbr + ((ct) * 8 + kk) * 1024);               \
  } while (0)

  #define MFMA32() do {                                                       \
    C0 = (f32x4){0.f, 0.f, 0.f, 0.f};                                         \
    C1 = (f32x4){0.f, 0.f, 0.f, 0.f};                                         \
    C2 = (f32x4){0.f, 0.f, 0.f, 0.f};                                         \
    C3 = (f32x4){0.f, 0.f, 0.f, 0.f};                                         \
    __builtin_amdgcn_s_setprio(1);                                            \
    _Pragma("unroll")                                                         \
    for (int kk = 0; kk < 8; ++kk) {                                          \
      C0 = __builtin_amdgcn_mfma_f32_16x16x32_bf16(af[0][kk], bfv[kk], C0, 0, 0, 0); \
      C1 = __builtin_amdgcn_mfma_f32_16x16x32_bf16(af[1][kk], bfv[kk], C1, 0, 0, 0); \
      C2 = __builtin_amdgcn_mfma_f32_16x16x32_bf16(af[2][kk], bfv[kk], C2, 0, 0, 0); \
      C3 = __builtin_amdgcn_mfma_f32_16x16x32_bf16(af[3][kk], bfv[kk], C3, 0, 0, 0); \
    }                                                                         \
    __builtin_amdgcn_s_setprio(0);                                            \
  } while (0)

  // flush: exps feed BOTH row accumulators and the per-phase col partial
  #define FLUSHC(ct) do {                                                     \
    float cs = 0.f;                                                           \
    _Pragma("unroll")                                                         \
    for (int r = 0; r < 4; ++r) {                                             \
      float e0 = FEXP2(C0[r]), e1 = FEXP2(C1[r]);                             \
      float e2 = FEXP2(C2[r]), e3 = FEXP2(C3[r]);                             \
      sacc[0][r] += e0; sacc[1][r] += e1;                                     \
      sacc[2][r] += e2; sacc[3][r] += e3;                                     \
      cs += (e0 + e1) + (e2 + e3);                                            \
    }                                                                         \
    cacc[ct] += cs;                                                           \
  } while (0)

  // prologue: stage JT 0 (strip square, cols ustrip*256), drain, barrier
  #pragma unroll
  for (int kk = 0; kk < 8; ++kk) STAGE_SLOT(0, ustrip * 256, kk);
  asm volatile("s_waitcnt vmcnt(0)" ::: "memory");
  __builtin_amdgcn_sched_barrier(0);
  __builtin_amdgcn_s_barrier();

  for (int jt = 0; jt < NJT; ++jt) {
    int nb = jt & 1;
    bool last = (jt == NJT - 1);
    int nj = jt + 1;
    int nextbase = (nj < 4) ? (ustrip * 256 + nj * 64) : (u16 * 256 + gg * 64);

    #pragma unroll
    for (int ct = 0; ct < 4; ++ct) {
      DSREAD(nb, ct);
      if (!last) {
        STAGE_SLOT(nb ^ 1, nextbase, 2 * ct);
        STAGE_SLOT(nb ^ 1, nextbase, 2 * ct + 1);
      }
      MFMA32();
      FLUSHC(ct);
    }

    bool harvest = (jt < 4) && (gg > 0);   // col-sums for strip d=gg>=1
    if (harvest) {
      #pragma unroll
      for (int c2 = 0; c2 < 4; ++c2) {
        float v = cacc[c2];
        v += __shfl_xor(v, 16, 64);
        v += __shfl_xor(v, 32, 64);
        if (kgrp == 0) cred[jt & 1][wave][c2 * 16 + lrow] = v;
      }
    }
    #pragma unroll
    for (int c2 = 0; c2 < 4; ++c2) cacc[c2] = 0.f;

    // square-end row flush: jt3 -> slot gg; jt4 (antipodal partial) -> 16+gg
    if (jt == 3 || jt == 4) {
      int slot = (jt == 3) ? gg : 16 + gg;
      #pragma unroll
      for (int rf = 0; rf < 4; ++rf) {
        #pragma unroll
        for (int r = 0; r < 4; ++r) {
          float v = sacc[rf][r];
          #pragma unroll
          for (int m = 1; m < 16; m <<= 1) v += __shfl_xor(v, m, 64);
          if (lrow == 0) {
            int grow = r0 + rf * 16 + kgrp * 4 + r;
            s_part[(size_t)grow * SSTRIDE + slot] = v;
          }
          sacc[rf][r] = 0.f;
        }
      }
    }

    asm volatile("s_waitcnt vmcnt(0)" ::: "memory");
    __builtin_amdgcn_sched_barrier(0);
    __builtin_amdgcn_s_barrier();

    // post-barrier: one (rotating) wave writes this JT's 64 col-sums
    if (harvest && wave == (jt & 3)) {
      int colrow = ustrip * 256 + jt * 64 + lane;
      float v = cred[jt & 1][0][lane] + cred[jt & 1][1][lane] +
                cred[jt & 1][2][lane] + cred[jt & 1][3][lane];
      s_part[(size_t)colrow * SSTRIDE + 19 + gg] = v;
    }
  }
  #undef FLUSHC
  #undef MFMA32
  #undef DSREAD
  #undef STAGE_SLOT
}

// ---------------- Kernel 3: per-row term (pos dot + assemble) --------------
// 512 blocks x 4 waves x 4 rows.
__global__ __launch_bounds__(256) void rowterm_kernel(
    const char* __restrict__ zb, const float* __restrict__ s_part,
    const float* __restrict__ selfdot, float* __restrict__ bpart) {
  int wave = threadIdx.x >> 6;
  int lane = threadIdx.x & 63;
  int rbase = blockIdx.x * 16 + wave * 4;
  float wacc = 0.f;
  #pragma unroll
  for (int rr = 0; rr < 4; ++rr) {
    int i = rbase + rr;
    int j = i ^ BHALF;                       // (i+B) mod 2B
    int wo = (lane * 8) ^ ((i & 7) << 4);    // j&7 == i&7 (4096 % 8 == 0)
    ushort4 zi = *(const ushort4*)(zb + (size_t)i * ROWB + wo);
    ushort4 zj = *(const ushort4*)(zb + (size_t)j * ROWB + wo);
    float dot = bfu(zi.x) * bfu(zj.x) + bfu(zi.y) * bfu(zj.y) +
                bfu(zi.z) * bfu(zj.z) + bfu(zi.w) * bfu(zj.w);
    float sp = (lane < NSLOT) ? s_part[(size_t)i * SSTRIDE + lane] : 0.f;
    #pragma unroll
    for (int m = 1; m < 64; m <<= 1) {
      dot += __shfl_xor(dot, m, 64);
      sp += __shfl_xor(sp, m, 64);
    }
    float S = sp - FEXP2(selfdot[i]);          // remove diagonal
    wacc += LN2F * (FLOG2(S) - dot);           // denom - pos (2's cancel)
  }
  __shared__ float red[4];
  if (lane == 0) red[wave] = wacc;
  __syncthreads();
  if (threadIdx.x == 0)
    bpart[blockIdx.x] = red[0] + red[1] + red[2] + red[3];
}

// ---------------- Kernel 4: final sum --------------------------------------
__global__ __launch_bounds__(512) void final_kernel(
    const float* __restrict__ bpart, float* __restrict__ out) {
  int t = threadIdx.x;  // 512 threads = 8 waves
  float v = bpart[t];
  #pragma unroll
  for (int m = 1; m < 64; m <<= 1) v += __shfl_xor(v, m, 64);
  __shared__ float r2[8];
  if ((t & 63) == 0) r2[t >> 6] = v;
  __syncthreads();
  if (t == 0) {
    float s = 0.f;
    #pragma unroll
    for (int w = 0; w < 8; ++w) s += r2[w];
    out[0] = s / (float)NROWS;
  }
}

// ---------------- Launcher --------------------------------------------------
extern "C" void kernel_launch(void* const* d_in, const int* in_sizes, int n_in,
                              void* d_out, int out_size, void* d_ws, size_t ws_size,
                              hipStream_t stream) {
  const float* a = (const float*)d_in[0];
  const float* b = (const float*)d_in[1];
  float* out = (float*)d_out;
  char* ws = (char*)d_ws;

  char* zb = ws;                                            // 4 MiB
  float* selfdot = (float*)(ws + (size_t)NROWS * ROWB);     // 32 KiB
  float* s_part = selfdot + NROWS;                          // 1.31 MiB
  float* bpart = s_part + (size_t)NROWS * SSTRIDE;          // 2 KiB

  hipLaunchKernelGGL(norm_kernel, dim3(NROWS / 4), dim3(256), 0, stream,
                     a, b, zb, selfdot);
  hipLaunchKernelGGL(sim_kernel, dim3(512), dim3(256), 0, stream,
                     zb, s_part);
  hipLaunchKernelGGL(rowterm_kernel, dim3(512), dim3(256), 0, stream,
                     zb, s_part, selfdot, bpart);
  hipLaunchKernelGGL(final_kernel, dim3(1), dim3(512), 0, stream, bpart, out);
}